// Round 21
// baseline (377.151 us; speedup 1.0000x reference)
//
#include <hip/hip_runtime.h>
#include <hip/hip_bf16.h>
#include <math.h>

// ---- types ----------------------------------------------------------------
typedef __attribute__((ext_vector_type(8))) __bf16 bf16x8;
typedef __attribute__((ext_vector_type(8))) short  s16x8;
typedef __attribute__((ext_vector_type(4))) float  f32x4;
union SB8 { s16x8 s; bf16x8 b; };

__device__ __forceinline__ unsigned short f2bf(float f) {
  unsigned int u = __builtin_bit_cast(unsigned int, f);
  u = u + 0x7FFFu + ((u >> 16) & 1u);           // round-to-nearest-even
  return (unsigned short)(u >> 16);
}

// async global->LDS, 16B per lane; LDS dest = wave-uniform base + lane*16
__device__ __forceinline__ void glds16(const void* g, void* l) {
  __builtin_amdgcn_global_load_lds((const __attribute__((address_space(1))) void*)g,
                                   (__attribute__((address_space(3))) void*)l, 16, 0, 0);
}

#define B_  256
#define S_  300
#define D_  512
#define SP  320          // keys padded to 320 (zero pad)
#define M_  76800        // B_*S_

// ---- K0: x fp32 -> bf16 (vectorized, 8 elems/iter) ------------------------
__global__ __launch_bounds__(256) void k_cvt_x(const float* __restrict__ x,
                                               unsigned short* __restrict__ xb, int n8) {
  int i = blockIdx.x * blockDim.x + threadIdx.x;
  int stride = gridDim.x * blockDim.x;
  for (; i < n8; i += stride) {
    const float4* p = (const float4*)(x + (size_t)i * 8);
    float4 a = p[0], b = p[1];
    union { unsigned short u[8]; s16x8 v; } o;
    o.u[0]=f2bf(a.x); o.u[1]=f2bf(a.y); o.u[2]=f2bf(a.z); o.u[3]=f2bf(a.w);
    o.u[4]=f2bf(b.x); o.u[5]=f2bf(b.y); o.u[6]=f2bf(b.z); o.u[7]=f2bf(b.w);
    *(s16x8*)(xb + (size_t)i * 8) = o.v;
  }
}

// ---- K0b: w -> wb01 (Wq,Wk row-major bf16) + wtv (Wv transposed bf16) -----
__global__ __launch_bounds__(256) void k_wt2(const float* __restrict__ w,
                                             unsigned short* __restrict__ wb01,
                                             unsigned short* __restrict__ wtv) {
  int i = blockIdx.x * 256 + threadIdx.x;       // exactly 3*512*512 threads
  int p = i >> 18;
  int r = i & 262143;
  unsigned short v = f2bf(w[i]);
  if (p < 2) {
    wb01[p * 262144 + r] = v;                   // row-major (coalesced)
  } else {
    int k = r >> 9, n = r & 511;
    wtv[n * 512 + k] = v;                       // n-major for k_projV
  }
}

// ---- K0c: Gjd[j][d] = sum_e Wk[j][e] * Wq[d][e]  (512x512, 16 blocks) -----
// Proven BK=64 dbuf GEMM body; A = wb1 (Wk rows j), B^T = wb0 (Wq rows d).
__global__ __launch_bounds__(256) void k_G(const unsigned short* __restrict__ wb01,
                                           unsigned short* __restrict__ gjd) {
  __shared__ short As[2][128 * 64];
  __shared__ short Bs[2][128 * 64];
  const unsigned short* wa = wb01 + 262144;     // Wk
  const unsigned short* wb = wb01;              // Wq
  int bid = blockIdx.x;                         // 16 = 4 x 4
  int mt = bid >> 2, n0 = (bid & 3) * 128;
  int rowBase = mt * 128;

  int tid = threadIdx.x, lane = tid & 63, wid = tid >> 6;
  int wr = wid >> 1, wc = wid & 1;
  int sr = lane >> 3;
  int ssg = ((lane & 7) ^ sr) * 8;
  int fr = lane & 15;
  int g  = lane >> 4;
  f32x4 acc[4][4] = {};

  for (int c = wid * 4; c < wid * 4 + 4; ++c) {
    glds16(wa + (size_t)(rowBase + c * 8 + sr) * 512 + ssg, &As[0][c * 512 + lane * 8]);
    glds16(wb + (size_t)(n0 + c * 8 + sr) * 512 + ssg, &Bs[0][c * 512 + lane * 8]);
  }
  __syncthreads();

  for (int t = 0; t < 8; ++t) {
    int cur = t & 1;
    if (t < 7) {
      int k0n = (t + 1) * 64;
      for (int c = wid * 4; c < wid * 4 + 4; ++c) {
        glds16(wa + (size_t)(rowBase + c * 8 + sr) * 512 + k0n + ssg,
               &As[cur ^ 1][c * 512 + lane * 8]);
        glds16(wb + (size_t)(n0 + c * 8 + sr) * 512 + k0n + ssg,
               &Bs[cur ^ 1][c * 512 + lane * 8]);
      }
    }
    SB8 aF[4][2], bF[4][2];
#pragma unroll
    for (int m = 0; m < 4; ++m) {
      int row = wr * 64 + m * 16 + fr;
#pragma unroll
      for (int kk = 0; kk < 2; ++kk) {
        int sl = ((kk << 2) + g) ^ (fr & 7);
        aF[m][kk].s = *(const s16x8*)&As[cur][row * 64 + sl * 8];
      }
    }
#pragma unroll
    for (int n = 0; n < 4; ++n) {
      int row = wc * 64 + n * 16 + fr;
#pragma unroll
      for (int kk = 0; kk < 2; ++kk) {
        int sl = ((kk << 2) + g) ^ (fr & 7);
        bF[n][kk].s = *(const s16x8*)&Bs[cur][row * 64 + sl * 8];
      }
    }
#pragma unroll
    for (int kk = 0; kk < 2; ++kk)
#pragma unroll
      for (int m = 0; m < 4; ++m)
#pragma unroll
        for (int n = 0; n < 4; ++n)
          acc[m][n] = __builtin_amdgcn_mfma_f32_16x16x32_bf16(aF[m][kk].b, bF[n][kk].b,
                                                              acc[m][n], 0, 0, 0);
    __syncthreads();
  }

  int fq = lane >> 4;
#pragma unroll
  for (int m = 0; m < 4; ++m)
#pragma unroll
    for (int n = 0; n < 4; ++n) {
      int row = rowBase + wr * 64 + m * 16 + fq * 4;
      int col = n0 + wc * 64 + n * 16 + fr;
      unsigned short* o = gjd + (size_t)row * 512 + col;
#pragma unroll
      for (int jj = 0; jj < 4; ++jj)
        o[(size_t)jj * 512] = f2bf(acc[m][n][jj]);
    }
}

// ---- K1a: T = xb . G  (replaces Q AND K projections via G = Wq Wk^T) ------
// ROUND-5 LOOP BODY VERBATIM; single projection; B^T = Gjd. T -> d_out.
__global__ __launch_bounds__(256) void k_projT(const unsigned short* __restrict__ xb,
                                               const unsigned short* __restrict__ gjd,
                                               unsigned short* __restrict__ Tout) {
  __shared__ short As[2][128 * 64];
  __shared__ short Bs[2][128 * 64];
  int bid = blockIdx.x;               // 2400 = 8 x 300; 300 = 75 x 4
  int xc = bid & 7, j = bid >> 3;
  int mt = xc + 8 * (j >> 2);
  int n0 = (j & 3) * 128;
  int rowBase = mt * 128;

  int tid = threadIdx.x, lane = tid & 63, wid = tid >> 6;
  int wr = wid >> 1, wc = wid & 1;
  int sr = lane >> 3;
  int ssg = ((lane & 7) ^ sr) * 8;
  int fr = lane & 15;
  int g  = lane >> 4;
  f32x4 acc[4][4] = {};

  for (int c = wid * 4; c < wid * 4 + 4; ++c) {
    glds16(xb + (size_t)(rowBase + c * 8 + sr) * 512 + ssg, &As[0][c * 512 + lane * 8]);
    glds16(gjd + (size_t)(n0 + c * 8 + sr) * 512 + ssg, &Bs[0][c * 512 + lane * 8]);
  }
  __syncthreads();

  for (int t = 0; t < 8; ++t) {
    int cur = t & 1;
    if (t < 7) {
      int k0n = (t + 1) * 64;
      for (int c = wid * 4; c < wid * 4 + 4; ++c) {
        glds16(xb + (size_t)(rowBase + c * 8 + sr) * 512 + k0n + ssg,
               &As[cur ^ 1][c * 512 + lane * 8]);
        glds16(gjd + (size_t)(n0 + c * 8 + sr) * 512 + k0n + ssg,
               &Bs[cur ^ 1][c * 512 + lane * 8]);
      }
    }
    SB8 aF[4][2], bF[4][2];
#pragma unroll
    for (int m = 0; m < 4; ++m) {
      int row = wr * 64 + m * 16 + fr;
#pragma unroll
      for (int kk = 0; kk < 2; ++kk) {
        int sl = ((kk << 2) + g) ^ (fr & 7);
        aF[m][kk].s = *(const s16x8*)&As[cur][row * 64 + sl * 8];
      }
    }
#pragma unroll
    for (int n = 0; n < 4; ++n) {
      int row = wc * 64 + n * 16 + fr;
#pragma unroll
      for (int kk = 0; kk < 2; ++kk) {
        int sl = ((kk << 2) + g) ^ (fr & 7);
        bF[n][kk].s = *(const s16x8*)&Bs[cur][row * 64 + sl * 8];
      }
    }
#pragma unroll
    for (int kk = 0; kk < 2; ++kk)
#pragma unroll
      for (int m = 0; m < 4; ++m)
#pragma unroll
        for (int n = 0; n < 4; ++n)
          acc[m][n] = __builtin_amdgcn_mfma_f32_16x16x32_bf16(aF[m][kk].b, bF[n][kk].b,
                                                              acc[m][n], 0, 0, 0);
    __syncthreads();
  }

  int fq = lane >> 4;
#pragma unroll
  for (int m = 0; m < 4; ++m)
#pragma unroll
    for (int n = 0; n < 4; ++n) {
      int row = rowBase + wr * 64 + m * 16 + fq * 4;
      int col = n0 + wc * 64 + n * 16 + fr;
      unsigned short* o = Tout + (size_t)row * 512 + col;
#pragma unroll
      for (int jj = 0; jj < 4; ++jj)
        o[(size_t)jj * 512] = f2bf(acc[m][n][jj]);
    }
}

// ---- K1b: V projection (p==2) -> Vt[b][512][320] (round-15 verbatim) ------
__global__ __launch_bounds__(256) void k_projV(const unsigned short* __restrict__ xb,
                                               const unsigned short* __restrict__ wtv,
                                               unsigned short* __restrict__ vt) {
  __shared__ short As[2][128 * 64];   // 2 x 16 KB (reused as T2, 32 KB)
  __shared__ short Bs[2][128 * 64];   // 2 x 16 KB
  int bid = blockIdx.x;               // 2400 = 8 x 300; 300 = 75 x 4
  int xc = bid & 7, j = bid >> 3;
  int mt = xc + 8 * (j >> 2);
  int n0 = (j & 3) * 128;
  int rowBase = mt * 128;
  const unsigned short* wp = wtv;

  int tid = threadIdx.x, lane = tid & 63, wid = tid >> 6;
  int wr = wid >> 1, wc = wid & 1;
  int sr = lane >> 3;
  int ssg = ((lane & 7) ^ sr) * 8;
  int fr = lane & 15;
  int g  = lane >> 4;
  f32x4 acc[4][4] = {};

  for (int c = wid * 4; c < wid * 4 + 4; ++c) {
    glds16(xb + (size_t)(rowBase + c * 8 + sr) * 512 + ssg, &As[0][c * 512 + lane * 8]);
    glds16(wp + (size_t)(n0 + c * 8 + sr) * 512 + ssg, &Bs[0][c * 512 + lane * 8]);
  }
  __syncthreads();

  for (int t = 0; t < 8; ++t) {
    int cur = t & 1;
    if (t < 7) {
      int k0n = (t + 1) * 64;
      for (int c = wid * 4; c < wid * 4 + 4; ++c) {
        glds16(xb + (size_t)(rowBase + c * 8 + sr) * 512 + k0n + ssg,
               &As[cur ^ 1][c * 512 + lane * 8]);
        glds16(wp + (size_t)(n0 + c * 8 + sr) * 512 + k0n + ssg,
               &Bs[cur ^ 1][c * 512 + lane * 8]);
      }
    }
    SB8 aF[4][2], bF[4][2];
#pragma unroll
    for (int m = 0; m < 4; ++m) {
      int row = wr * 64 + m * 16 + fr;
#pragma unroll
      for (int kk = 0; kk < 2; ++kk) {
        int sl = ((kk << 2) + g) ^ (fr & 7);
        aF[m][kk].s = *(const s16x8*)&As[cur][row * 64 + sl * 8];
      }
    }
#pragma unroll
    for (int n = 0; n < 4; ++n) {
      int row = wc * 64 + n * 16 + fr;
#pragma unroll
      for (int kk = 0; kk < 2; ++kk) {
        int sl = ((kk << 2) + g) ^ (fr & 7);
        bF[n][kk].s = *(const s16x8*)&Bs[cur][row * 64 + sl * 8];
      }
    }
#pragma unroll
    for (int kk = 0; kk < 2; ++kk)
#pragma unroll
      for (int m = 0; m < 4; ++m)
#pragma unroll
        for (int n = 0; n < 4; ++n)
          acc[m][n] = __builtin_amdgcn_mfma_f32_16x16x32_bf16(aF[m][kk].b, bF[n][kk].b,
                                                              acc[m][n], 0, 0, 0);
    __syncthreads();
  }

  // epilogue v2 (round-15 proven): n-major swizzled T2, coalesced 8B stores
  int fq = lane >> 4;
  short* T2 = &As[0][0];                   // 16384 shorts = [128 n][128 s']
#pragma unroll
  for (int m = 0; m < 4; ++m) {
    int s0 = wr * 64 + m * 16 + fq * 4;
#pragma unroll
    for (int n16 = 0; n16 < 4; ++n16) {
      int c = wc * 64 + n16 * 16 + fr;
      int idx = c * 128 + (s0 ^ ((c & 7) << 4));
      union { unsigned short u[4]; uint2 v; } w;
#pragma unroll
      for (int jj = 0; jj < 4; ++jj) w.u[jj] = f2bf(acc[m][n16][jj]);
      *(uint2*)&T2[idx] = w.v;
    }
  }
  __syncthreads();
  for (int i = 0; i < 8; ++i) {
    int u = i * 256 + tid;
    int n = u >> 4, ch = u & 15;
    int idx = n * 128 + ((ch * 8) ^ ((n & 7) << 4));
    s16x8 vv = *(const s16x8*)&T2[idx];
    size_t ncol = (size_t)(n0 + n);
#pragma unroll
    for (int h = 0; h < 2; ++h) {
      int gs = rowBase + ch * 8 + h * 4;
      int bb = (unsigned)gs / 300u;
      int sloc = gs - bb * 300;
      union { unsigned short u[4]; uint2 v; } w;
#pragma unroll
      for (int e = 0; e < 4; ++e) w.u[e] = (unsigned short)vv[h * 4 + e];
      *(uint2*)(vt + (size_t)bb * (512 * SP) + ncol * SP + sloc) = w.v;
    }
  }
}

// ---- K2: P = softmax(T x^T / sqrt(300)) per (batch, 32-row q-tile) --------
// v9: explicit 2-deep REGISTER double-buffer (named A/B fragment sets,
// parity static under #pragma unroll -- rule #20). v8's 68 VGPRs held only
// ONE iteration's loads in flight -> each iter stalled ~300cyc on L2/L3
// latency. Prefetching t+1 before t's MFMAs doubles latency depth; VGPR
// rises to ~120 which is FREE (occupancy is LDS-capped at 3 blocks/CU,
// allowing up to ~170 VGPR/wave).
__global__ __launch_bounds__(256) void k_attn_p(const unsigned short* __restrict__ Q,
                                                const unsigned short* __restrict__ K,
                                                unsigned short* __restrict__ P) {
  __shared__ float S[32 * 321];              // 41,088 B
  int bid = blockIdx.x;
  int xcd = bid & 7, slot = bid >> 3;
  int b = xcd * 32 + slot / 10;
  int qt = slot % 10;
  int qBase = qt * 32;
  const unsigned short* Qb = Q + (size_t)b * S_ * 512;
  const unsigned short* Kb = K + (size_t)b * S_ * 512;
  unsigned short* Pb = P + (size_t)b * S_ * SP;
  int tid = threadIdx.x, lane = tid & 63, wid = tid >> 6;
  int kg = (lane >> 4) * 8, fr = lane & 15;
  int g = lane >> 4;

  int qr0 = qBase + fr;      if (qr0 > 299) qr0 = 299;
  int qr1 = qBase + 16 + fr; if (qr1 > 299) qr1 = 299;
  const unsigned short* Qr0 = Qb + (size_t)qr0 * 512 + kg;
  const unsigned short* Qr1 = Qb + (size_t)qr1 * 512 + kg;

  int ntBase = wid * 5;
  const unsigned short* Kr[5];
#pragma unroll
  for (int n = 0; n < 5; ++n) {
    int kr = (ntBase + n) * 16 + fr; if (kr > 299) kr = 299;
    Kr[n] = Kb + (size_t)kr * 512 + kg;
  }

  f32x4 acc[2][5] = {};
  SB8 qA[2], kA[5], qB[2], kB[5];
  // prologue: t=0 into A
  qA[0].s = *(const s16x8*)(Qr0);
  qA[1].s = *(const s16x8*)(Qr1);
#pragma unroll
  for (int n = 0; n < 5; ++n) kA[n].s = *(const s16x8*)(Kr[n]);

#pragma unroll
  for (int t = 0; t < 16; ++t) {
    if ((t & 1) == 0) {
      if (t < 15) {                          // prefetch t+1 into B
        int k1 = (t + 1) * 32;
        qB[0].s = *(const s16x8*)(Qr0 + k1);
        qB[1].s = *(const s16x8*)(Qr1 + k1);
#pragma unroll
        for (int n = 0; n < 5; ++n) kB[n].s = *(const s16x8*)(Kr[n] + k1);
      }
#pragma unroll
      for (int m = 0; m < 2; ++m)
#pragma unroll
        for (int n = 0; n < 5; ++n)
          acc[m][n] = __builtin_amdgcn_mfma_f32_16x16x32_bf16(
              (m ? qA[1].b : qA[0].b), kA[n].b, acc[m][n], 0, 0, 0);
    } else {
      if (t < 15) {                          // prefetch t+1 into A
        int k1 = (t + 1) * 32;
        qA[0].s = *(const s16x8*)(Qr0 + k1);
        qA[1].s = *(const s16x8*)(Qr1 + k1);
#pragma unroll
        for (int n = 0; n < 5; ++n) kA[n].s = *(const s16x8*)(Kr[n] + k1);
      }
#pragma unroll
      for (int m = 0; m < 2; ++m)
#pragma unroll
        for (int n = 0; n < 5; ++n)
          acc[m][n] = __builtin_amdgcn_mfma_f32_16x16x32_bf16(
              (m ? qB[1].b : qB[0].b), kB[n].b, acc[m][n], 0, 0, 0);
    }
  }

  const float scale = 0.05773502691896258f;      // 1/sqrt(300)
#pragma unroll
  for (int m = 0; m < 2; ++m)
#pragma unroll
    for (int n = 0; n < 5; ++n) {
      int col = (ntBase + n) * 16 + fr;
      int rb = m * 16 + g * 4;
#pragma unroll
      for (int jj = 0; jj < 4; ++jj)
        S[(rb + jj) * 321 + col] = acc[m][n][jj] * scale;
    }
  __syncthreads();                               // the ONLY barrier

  {
    int r = tid >> 3, jj = tid & 7;
    int c0 = jj * 40;
    int cend = c0 + 40; if (cend > 300) cend = 300;
    float* Sr = &S[r * 321];
    float m0 = -1e30f, m1 = -1e30f, m2 = -1e30f, m3 = -1e30f;
    for (int c = c0; c < cend; c += 4) {
      m0 = fmaxf(m0, Sr[c]);     m1 = fmaxf(m1, Sr[c + 1]);
      m2 = fmaxf(m2, Sr[c + 2]); m3 = fmaxf(m3, Sr[c + 3]);
    }
    float mx = fmaxf(fmaxf(m0, m1), fmaxf(m2, m3));
    mx = fmaxf(mx, __shfl_xor(mx, 1));
    mx = fmaxf(mx, __shfl_xor(mx, 2));
    mx = fmaxf(mx, __shfl_xor(mx, 4));
    float s0 = 0.f, s1 = 0.f, s2 = 0.f, s3 = 0.f;
    for (int c = c0; c < cend; c += 4) {
      float e0 = __expf(Sr[c] - mx);     Sr[c] = e0;     s0 += e0;
      float e1 = __expf(Sr[c + 1] - mx); Sr[c + 1] = e1; s1 += e1;
      float e2 = __expf(Sr[c + 2] - mx); Sr[c + 2] = e2; s2 += e2;
      float e3 = __expf(Sr[c + 3] - mx); Sr[c + 3] = e3; s3 += e3;
    }
    float sum = (s0 + s1) + (s2 + s3);
    sum += __shfl_xor(sum, 1);
    sum += __shfl_xor(sum, 2);
    sum += __shfl_xor(sum, 4);
    float inv = 1.0f / sum;
    int qrow = qBase + r;
    if (qrow < 300) {
#pragma unroll
      for (int i = 0; i < 5; ++i) {
        int cb = c0 + i * 8;
        union { unsigned short u[8]; s16x8 v; } o;
#pragma unroll
        for (int e = 0; e < 8; ++e) {
          int cc = cb + e;
          o.u[e] = (cc < 300) ? f2bf(Sr[cc] * inv) : (unsigned short)0;
        }
        *(s16x8*)(Pb + (size_t)qrow * SP + cb) = o.v;
      }
    }
  }
}

// ---- K3: O = P @ V  (A = P [300][320], B^T = Vt [512][320], C fp32) -------
__global__ __launch_bounds__(256) void k_pv(const unsigned short* __restrict__ P,
                                            const unsigned short* __restrict__ Vt,
                                            float* __restrict__ O) {
  __shared__ short As[128 * 32];
  __shared__ short Bs[128 * 32];
  int bid = blockIdx.x;                       // 3072 = 8*384, 384 = 32*12
  int xc = bid & 7, j = bid >> 3;
  int b = xc + 8 * (j / 12);
  int tile = j % 12;
  int mt = tile >> 2, n0 = (tile & 3) * 128;
  int rowBase = mt * 128;
  const unsigned short* Pb  = P  + (size_t)b * S_ * SP;
  const unsigned short* Vtb = Vt + (size_t)b * 512 * SP;
  float* Ob = O + (size_t)b * S_ * 512;
  int tid = threadIdx.x, lane = tid & 63, wid = tid >> 6;
  int wr = wid >> 1, wc = wid & 1;
  int sr4 = lane >> 2;
  int ss = ((lane & 3) ^ ((lane >> 3) & 3)) * 8;
  int fr = lane & 15;
  int g = lane >> 4;
  int sl = (g ^ ((fr >> 1) & 3)) * 8;
  f32x4 acc[4][4] = {};

  for (int t = 0; t < 10; ++t) {
    int k0 = t * 32;
    for (int c = wid * 2; c < wid * 2 + 2; ++c) {
      int row = rowBase + c * 16 + sr4; if (row > 299) row = 299;
      glds16(Pb + (size_t)row * SP + k0 + ss, &As[c * 512 + lane * 8]);
    }
    for (int c = wid * 2; c < wid * 2 + 2; ++c)
      glds16(Vtb + (size_t)(n0 + c * 16 + sr4) * SP + k0 + ss,
             &Bs[c * 512 + lane * 8]);
    __syncthreads();
    SB8 aF[4], bF[4];
#pragma unroll
    for (int m = 0; m < 4; ++m) {
      int row = wr * 64 + m * 16 + fr;
      aF[m].s = *(const s16x8*)&As[row * 32 + sl];
    }
#pragma unroll
    for (int n = 0; n < 4; ++n) {
      int row = wc * 64 + n * 16 + fr;
      bF[n].s = *(const s16x8*)&Bs[row * 32 + sl];
    }
#pragma unroll
    for (int m = 0; m < 4; ++m)
#pragma unroll
      for (int n = 0; n < 4; ++n)
        acc[m][n] = __builtin_amdgcn_mfma_f32_16x16x32_bf16(aF[m].b, bF[n].b, acc[m][n], 0, 0, 0);
    __syncthreads();
  }
  int fq = lane >> 4;
#pragma unroll
  for (int m = 0; m < 4; ++m)
#pragma unroll
    for (int n = 0; n < 4; ++n) {
      int col = n0 + wc * 64 + n * 16 + fr;
#pragma unroll
      for (int jj = 0; jj < 4; ++jj) {
        int row = rowBase + wr * 64 + m * 16 + fq * 4 + jj;
        if (row < 300) Ob[(size_t)row * 512 + col] = acc[m][n][jj];
      }
    }
}

// ---- launcher --------------------------------------------------------------
// G-trick pipeline (round-20 proven): G = WqWk^T; T = xb.G; k_attn_p K = xb.
// ws: Vt@0 (83.9M), xb@83.9M (78.6M), P@162.5M (49.2M), wtv@211.7M (0.5M),
// wb01@212.2M (1.0M), Gjd@213.3M (0.5M) = 213.8 MB total.
extern "C" void kernel_launch(void* const* d_in, const int* in_sizes, int n_in,
                              void* d_out, int out_size, void* d_ws, size_t ws_size,
                              hipStream_t stream) {
  const float* x = (const float*)d_in[0];
  const float* w = (const float*)d_in[1];
  float* out = (float*)d_out;
  char* ws = (char*)d_ws;

  unsigned short* Tq   = (unsigned short*)d_out;              // T in d_out
  unsigned short* Vt   = (unsigned short*)(ws);               // 83,886,080 B
  unsigned short* xb   = (unsigned short*)(ws + 83886080LL);  // 78,643,200 B
  unsigned short* Pp   = (unsigned short*)(ws + 162529280LL); // 49,152,000 B
  unsigned short* wtv  = (unsigned short*)(ws + 211681280LL); // 524,288 B
  unsigned short* wb01 = (unsigned short*)(ws + 212205568LL); // 1,048,576 B
  unsigned short* Gjd  = (unsigned short*)(ws + 213254144LL); // 524,288 B

  k_cvt_x<<<2048, 256, 0, stream>>>(x, xb, 4915200);
  k_wt2<<<3072, 256, 0, stream>>>(w, wb01, wtv);
  k_G<<<16, 256, 0, stream>>>(wb01, Gjd);
  k_projT<<<2400, 256, 0, stream>>>(xb, Gjd, Tq);             // T -> d_out
  k_attn_p<<<2560, 256, 0, stream>>>(Tq, xb, Pp);             // K == xb
  k_projV<<<2400, 256, 0, stream>>>(xb, wtv, Vt);
  k_pv<<<3072, 256, 0, stream>>>(Pp, Vt, out);                // overwrites T
}

// Round 22
// 365.059 us; speedup vs baseline: 1.0331x; 1.0331x over previous
//
#include <hip/hip_runtime.h>
#include <hip/hip_bf16.h>
#include <math.h>

// ---- types ----------------------------------------------------------------
typedef __attribute__((ext_vector_type(8))) __bf16 bf16x8;
typedef __attribute__((ext_vector_type(8))) short  s16x8;
typedef __attribute__((ext_vector_type(4))) float  f32x4;
union SB8 { s16x8 s; bf16x8 b; };

__device__ __forceinline__ unsigned short f2bf(float f) {
  unsigned int u = __builtin_bit_cast(unsigned int, f);
  u = u + 0x7FFFu + ((u >> 16) & 1u);           // round-to-nearest-even
  return (unsigned short)(u >> 16);
}

// async global->LDS, 16B per lane; LDS dest = wave-uniform base + lane*16
__device__ __forceinline__ void glds16(const void* g, void* l) {
  __builtin_amdgcn_global_load_lds((const __attribute__((address_space(1))) void*)g,
                                   (__attribute__((address_space(3))) void*)l, 16, 0, 0);
}

#define B_  256
#define S_  300
#define D_  512
#define SP  320          // keys padded to 320 (zero pad)
#define M_  76800        // B_*S_
#define XS  544          // padded row stride (shorts) for xb and T: 1088 B
                         // = 4.25 x 256B -> 16 consecutive rows cover all 16
                         // L2 channels / 16 distinct L1 sets (1024B stride
                         // aliased 16 rows into 4 -> the ~850GB/s ceiling)

// ---- K0: x fp32 -> bf16, PADDED rows (512 data + 32 pad shorts) -----------
__global__ __launch_bounds__(256) void k_cvt_x(const float* __restrict__ x,
                                               unsigned short* __restrict__ xb, int n8) {
  int i = blockIdx.x * blockDim.x + threadIdx.x;
  int stride = gridDim.x * blockDim.x;
  for (; i < n8; i += stride) {
    const float4* p = (const float4*)(x + (size_t)i * 8);
    float4 a = p[0], b = p[1];
    union { unsigned short u[8]; s16x8 v; } o;
    o.u[0]=f2bf(a.x); o.u[1]=f2bf(a.y); o.u[2]=f2bf(a.z); o.u[3]=f2bf(a.w);
    o.u[4]=f2bf(b.x); o.u[5]=f2bf(b.y); o.u[6]=f2bf(b.z); o.u[7]=f2bf(b.w);
    int row = i >> 6, c8 = i & 63;               // 64 chunks of 8 per row
    *(s16x8*)(xb + (size_t)row * XS + c8 * 8) = o.v;
  }
}

// ---- K0b: w -> wb01 (Wq,Wk row-major bf16) + wtv (Wv transposed bf16) -----
__global__ __launch_bounds__(256) void k_wt2(const float* __restrict__ w,
                                             unsigned short* __restrict__ wb01,
                                             unsigned short* __restrict__ wtv) {
  int i = blockIdx.x * 256 + threadIdx.x;       // exactly 3*512*512 threads
  int p = i >> 18;
  int r = i & 262143;
  unsigned short v = f2bf(w[i]);
  if (p < 2) {
    wb01[p * 262144 + r] = v;                   // row-major (coalesced)
  } else {
    int k = r >> 9, n = r & 511;
    wtv[n * 512 + k] = v;                       // n-major for k_projV
  }
}

// ---- K0c: Gjd[j][d] = sum_e Wk[j][e] * Wq[d][e]  (512x512, 16 blocks) -----
__global__ __launch_bounds__(256) void k_G(const unsigned short* __restrict__ wb01,
                                           unsigned short* __restrict__ gjd) {
  __shared__ short As[2][128 * 64];
  __shared__ short Bs[2][128 * 64];
  const unsigned short* wa = wb01 + 262144;     // Wk
  const unsigned short* wb = wb01;              // Wq
  int bid = blockIdx.x;                         // 16 = 4 x 4
  int mt = bid >> 2, n0 = (bid & 3) * 128;
  int rowBase = mt * 128;

  int tid = threadIdx.x, lane = tid & 63, wid = tid >> 6;
  int wr = wid >> 1, wc = wid & 1;
  int sr = lane >> 3;
  int ssg = ((lane & 7) ^ sr) * 8;
  int fr = lane & 15;
  int g  = lane >> 4;
  f32x4 acc[4][4] = {};

  for (int c = wid * 4; c < wid * 4 + 4; ++c) {
    glds16(wa + (size_t)(rowBase + c * 8 + sr) * 512 + ssg, &As[0][c * 512 + lane * 8]);
    glds16(wb + (size_t)(n0 + c * 8 + sr) * 512 + ssg, &Bs[0][c * 512 + lane * 8]);
  }
  __syncthreads();

  for (int t = 0; t < 8; ++t) {
    int cur = t & 1;
    if (t < 7) {
      int k0n = (t + 1) * 64;
      for (int c = wid * 4; c < wid * 4 + 4; ++c) {
        glds16(wa + (size_t)(rowBase + c * 8 + sr) * 512 + k0n + ssg,
               &As[cur ^ 1][c * 512 + lane * 8]);
        glds16(wb + (size_t)(n0 + c * 8 + sr) * 512 + k0n + ssg,
               &Bs[cur ^ 1][c * 512 + lane * 8]);
      }
    }
    SB8 aF[4][2], bF[4][2];
#pragma unroll
    for (int m = 0; m < 4; ++m) {
      int row = wr * 64 + m * 16 + fr;
#pragma unroll
      for (int kk = 0; kk < 2; ++kk) {
        int sl = ((kk << 2) + g) ^ (fr & 7);
        aF[m][kk].s = *(const s16x8*)&As[cur][row * 64 + sl * 8];
      }
    }
#pragma unroll
    for (int n = 0; n < 4; ++n) {
      int row = wc * 64 + n * 16 + fr;
#pragma unroll
      for (int kk = 0; kk < 2; ++kk) {
        int sl = ((kk << 2) + g) ^ (fr & 7);
        bF[n][kk].s = *(const s16x8*)&Bs[cur][row * 64 + sl * 8];
      }
    }
#pragma unroll
    for (int kk = 0; kk < 2; ++kk)
#pragma unroll
      for (int m = 0; m < 4; ++m)
#pragma unroll
        for (int n = 0; n < 4; ++n)
          acc[m][n] = __builtin_amdgcn_mfma_f32_16x16x32_bf16(aF[m][kk].b, bF[n][kk].b,
                                                              acc[m][n], 0, 0, 0);
    __syncthreads();
  }

  int fq = lane >> 4;
#pragma unroll
  for (int m = 0; m < 4; ++m)
#pragma unroll
    for (int n = 0; n < 4; ++n) {
      int row = rowBase + wr * 64 + m * 16 + fq * 4;
      int col = n0 + wc * 64 + n * 16 + fr;
      unsigned short* o = gjd + (size_t)row * 512 + col;
#pragma unroll
      for (int jj = 0; jj < 4; ++jj)
        o[(size_t)jj * 512] = f2bf(acc[m][n][jj]);
    }
}

// ---- K1a: T = xb . G  (single score-side projection; G = Wq Wk^T) ---------
// ROUND-5 LOOP BODY; xb read and T written at PADDED stride XS.
__global__ __launch_bounds__(256) void k_projT(const unsigned short* __restrict__ xb,
                                               const unsigned short* __restrict__ gjd,
                                               unsigned short* __restrict__ Tout) {
  __shared__ short As[2][128 * 64];
  __shared__ short Bs[2][128 * 64];
  int bid = blockIdx.x;               // 2400 = 8 x 300; 300 = 75 x 4
  int xc = bid & 7, j = bid >> 3;
  int mt = xc + 8 * (j >> 2);
  int n0 = (j & 3) * 128;
  int rowBase = mt * 128;

  int tid = threadIdx.x, lane = tid & 63, wid = tid >> 6;
  int wr = wid >> 1, wc = wid & 1;
  int sr = lane >> 3;
  int ssg = ((lane & 7) ^ sr) * 8;
  int fr = lane & 15;
  int g  = lane >> 4;
  f32x4 acc[4][4] = {};

  for (int c = wid * 4; c < wid * 4 + 4; ++c) {
    glds16(xb + (size_t)(rowBase + c * 8 + sr) * XS + ssg, &As[0][c * 512 + lane * 8]);
    glds16(gjd + (size_t)(n0 + c * 8 + sr) * 512 + ssg, &Bs[0][c * 512 + lane * 8]);
  }
  __syncthreads();

  for (int t = 0; t < 8; ++t) {
    int cur = t & 1;
    if (t < 7) {
      int k0n = (t + 1) * 64;
      for (int c = wid * 4; c < wid * 4 + 4; ++c) {
        glds16(xb + (size_t)(rowBase + c * 8 + sr) * XS + k0n + ssg,
               &As[cur ^ 1][c * 512 + lane * 8]);
        glds16(gjd + (size_t)(n0 + c * 8 + sr) * 512 + k0n + ssg,
               &Bs[cur ^ 1][c * 512 + lane * 8]);
      }
    }
    SB8 aF[4][2], bF[4][2];
#pragma unroll
    for (int m = 0; m < 4; ++m) {
      int row = wr * 64 + m * 16 + fr;
#pragma unroll
      for (int kk = 0; kk < 2; ++kk) {
        int sl = ((kk << 2) + g) ^ (fr & 7);
        aF[m][kk].s = *(const s16x8*)&As[cur][row * 64 + sl * 8];
      }
    }
#pragma unroll
    for (int n = 0; n < 4; ++n) {
      int row = wc * 64 + n * 16 + fr;
#pragma unroll
      for (int kk = 0; kk < 2; ++kk) {
        int sl = ((kk << 2) + g) ^ (fr & 7);
        bF[n][kk].s = *(const s16x8*)&Bs[cur][row * 64 + sl * 8];
      }
    }
#pragma unroll
    for (int kk = 0; kk < 2; ++kk)
#pragma unroll
      for (int m = 0; m < 4; ++m)
#pragma unroll
        for (int n = 0; n < 4; ++n)
          acc[m][n] = __builtin_amdgcn_mfma_f32_16x16x32_bf16(aF[m][kk].b, bF[n][kk].b,
                                                              acc[m][n], 0, 0, 0);
    __syncthreads();
  }

  int fq = lane >> 4;
#pragma unroll
  for (int m = 0; m < 4; ++m)
#pragma unroll
    for (int n = 0; n < 4; ++n) {
      int row = rowBase + wr * 64 + m * 16 + fq * 4;
      int col = n0 + wc * 64 + n * 16 + fr;
      unsigned short* o = Tout + (size_t)row * XS + col;
#pragma unroll
      for (int jj = 0; jj < 4; ++jj)
        o[(size_t)jj * XS] = f2bf(acc[m][n][jj]);
    }
}

// ---- K1b: V projection -> Vt[b][512][320]; xb read at padded stride -------
__global__ __launch_bounds__(256) void k_projV(const unsigned short* __restrict__ xb,
                                               const unsigned short* __restrict__ wtv,
                                               unsigned short* __restrict__ vt) {
  __shared__ short As[2][128 * 64];   // 2 x 16 KB (reused as T2, 32 KB)
  __shared__ short Bs[2][128 * 64];   // 2 x 16 KB
  int bid = blockIdx.x;               // 2400 = 8 x 300; 300 = 75 x 4
  int xc = bid & 7, j = bid >> 3;
  int mt = xc + 8 * (j >> 2);
  int n0 = (j & 3) * 128;
  int rowBase = mt * 128;
  const unsigned short* wp = wtv;

  int tid = threadIdx.x, lane = tid & 63, wid = tid >> 6;
  int wr = wid >> 1, wc = wid & 1;
  int sr = lane >> 3;
  int ssg = ((lane & 7) ^ sr) * 8;
  int fr = lane & 15;
  int g  = lane >> 4;
  f32x4 acc[4][4] = {};

  for (int c = wid * 4; c < wid * 4 + 4; ++c) {
    glds16(xb + (size_t)(rowBase + c * 8 + sr) * XS + ssg, &As[0][c * 512 + lane * 8]);
    glds16(wp + (size_t)(n0 + c * 8 + sr) * 512 + ssg, &Bs[0][c * 512 + lane * 8]);
  }
  __syncthreads();

  for (int t = 0; t < 8; ++t) {
    int cur = t & 1;
    if (t < 7) {
      int k0n = (t + 1) * 64;
      for (int c = wid * 4; c < wid * 4 + 4; ++c) {
        glds16(xb + (size_t)(rowBase + c * 8 + sr) * XS + k0n + ssg,
               &As[cur ^ 1][c * 512 + lane * 8]);
        glds16(wp + (size_t)(n0 + c * 8 + sr) * 512 + k0n + ssg,
               &Bs[cur ^ 1][c * 512 + lane * 8]);
      }
    }
    SB8 aF[4][2], bF[4][2];
#pragma unroll
    for (int m = 0; m < 4; ++m) {
      int row = wr * 64 + m * 16 + fr;
#pragma unroll
      for (int kk = 0; kk < 2; ++kk) {
        int sl = ((kk << 2) + g) ^ (fr & 7);
        aF[m][kk].s = *(const s16x8*)&As[cur][row * 64 + sl * 8];
      }
    }
#pragma unroll
    for (int n = 0; n < 4; ++n) {
      int row = wc * 64 + n * 16 + fr;
#pragma unroll
      for (int kk = 0; kk < 2; ++kk) {
        int sl = ((kk << 2) + g) ^ (fr & 7);
        bF[n][kk].s = *(const s16x8*)&Bs[cur][row * 64 + sl * 8];
      }
    }
#pragma unroll
    for (int kk = 0; kk < 2; ++kk)
#pragma unroll
      for (int m = 0; m < 4; ++m)
#pragma unroll
        for (int n = 0; n < 4; ++n)
          acc[m][n] = __builtin_amdgcn_mfma_f32_16x16x32_bf16(aF[m][kk].b, bF[n][kk].b,
                                                              acc[m][n], 0, 0, 0);
    __syncthreads();
  }

  // epilogue v2 (round-15 proven): n-major swizzled T2, coalesced 8B stores
  int fq = lane >> 4;
  short* T2 = &As[0][0];                   // 16384 shorts = [128 n][128 s']
#pragma unroll
  for (int m = 0; m < 4; ++m) {
    int s0 = wr * 64 + m * 16 + fq * 4;
#pragma unroll
    for (int n16 = 0; n16 < 4; ++n16) {
      int c = wc * 64 + n16 * 16 + fr;
      int idx = c * 128 + (s0 ^ ((c & 7) << 4));
      union { unsigned short u[4]; uint2 v; } w;
#pragma unroll
      for (int jj = 0; jj < 4; ++jj) w.u[jj] = f2bf(acc[m][n16][jj]);
      *(uint2*)&T2[idx] = w.v;
    }
  }
  __syncthreads();
  for (int i = 0; i < 8; ++i) {
    int u = i * 256 + tid;
    int n = u >> 4, ch = u & 15;
    int idx = n * 128 + ((ch * 8) ^ ((n & 7) << 4));
    s16x8 vv = *(const s16x8*)&T2[idx];
    size_t ncol = (size_t)(n0 + n);
#pragma unroll
    for (int h = 0; h < 2; ++h) {
      int gs = rowBase + ch * 8 + h * 4;
      int bb = (unsigned)gs / 300u;
      int sloc = gs - bb * 300;
      union { unsigned short u[4]; uint2 v; } w;
#pragma unroll
      for (int e = 0; e < 4; ++e) w.u[e] = (unsigned short)vv[h * 4 + e];
      *(uint2*)(vt + (size_t)bb * (512 * SP) + ncol * SP + sloc) = w.v;
    }
  }
}

// ---- K2: P = softmax(T x^T / sqrt(300)) per (batch, 32-row q-tile) --------
// v10 = v8 body with PADDED strides (XS=544): the 1024B row stride aliased
// every load's 16 rows into 4 L1 sets / 4 L2 channels -> ~4x serialization,
// the invariant behind six identical-latency variants. 1088B stride covers
// all 16 channels/sets.
__global__ __launch_bounds__(256) void k_attn_p(const unsigned short* __restrict__ Q,
                                                const unsigned short* __restrict__ K,
                                                unsigned short* __restrict__ P) {
  __shared__ float S[32 * 321];              // 41,088 B
  int bid = blockIdx.x;
  int xcd = bid & 7, slot = bid >> 3;
  int b = xcd * 32 + slot / 10;
  int qt = slot % 10;
  int qBase = qt * 32;
  const unsigned short* Qb = Q + (size_t)b * S_ * XS;
  const unsigned short* Kb = K + (size_t)b * S_ * XS;
  unsigned short* Pb = P + (size_t)b * S_ * SP;
  int tid = threadIdx.x, lane = tid & 63, wid = tid >> 6;
  int kg = (lane >> 4) * 8, fr = lane & 15;
  int g = lane >> 4;

  int qr0 = qBase + fr;      if (qr0 > 299) qr0 = 299;
  int qr1 = qBase + 16 + fr; if (qr1 > 299) qr1 = 299;
  const unsigned short* Qr0 = Qb + (size_t)qr0 * XS + kg;
  const unsigned short* Qr1 = Qb + (size_t)qr1 * XS + kg;

  int ntBase = wid * 5;
  const unsigned short* Kr[5];
#pragma unroll
  for (int n = 0; n < 5; ++n) {
    int kr = (ntBase + n) * 16 + fr; if (kr > 299) kr = 299;
    Kr[n] = Kb + (size_t)kr * XS + kg;
  }

  f32x4 acc[2][5] = {};
#pragma unroll
  for (int t = 0; t < 16; ++t) {
    int k0 = t * 32;
    SB8 qF[2], kF[5];
    qF[0].s = *(const s16x8*)(Qr0 + k0);
    qF[1].s = *(const s16x8*)(Qr1 + k0);
#pragma unroll
    for (int n = 0; n < 5; ++n)
      kF[n].s = *(const s16x8*)(Kr[n] + k0);
#pragma unroll
    for (int m = 0; m < 2; ++m)
#pragma unroll
      for (int n = 0; n < 5; ++n)
        acc[m][n] = __builtin_amdgcn_mfma_f32_16x16x32_bf16(qF[m].b, kF[n].b, acc[m][n], 0, 0, 0);
  }

  const float scale = 0.05773502691896258f;      // 1/sqrt(300)
#pragma unroll
  for (int m = 0; m < 2; ++m)
#pragma unroll
    for (int n = 0; n < 5; ++n) {
      int col = (ntBase + n) * 16 + fr;
      int rb = m * 16 + g * 4;
#pragma unroll
      for (int jj = 0; jj < 4; ++jj)
        S[(rb + jj) * 321 + col] = acc[m][n][jj] * scale;
    }
  __syncthreads();                               // the ONLY barrier

  {
    int r = tid >> 3, jj = tid & 7;
    int c0 = jj * 40;
    int cend = c0 + 40; if (cend > 300) cend = 300;
    float* Sr = &S[r * 321];
    float m0 = -1e30f, m1 = -1e30f, m2 = -1e30f, m3 = -1e30f;
    for (int c = c0; c < cend; c += 4) {
      m0 = fmaxf(m0, Sr[c]);     m1 = fmaxf(m1, Sr[c + 1]);
      m2 = fmaxf(m2, Sr[c + 2]); m3 = fmaxf(m3, Sr[c + 3]);
    }
    float mx = fmaxf(fmaxf(m0, m1), fmaxf(m2, m3));
    mx = fmaxf(mx, __shfl_xor(mx, 1));
    mx = fmaxf(mx, __shfl_xor(mx, 2));
    mx = fmaxf(mx, __shfl_xor(mx, 4));
    float s0 = 0.f, s1 = 0.f, s2 = 0.f, s3 = 0.f;
    for (int c = c0; c < cend; c += 4) {
      float e0 = __expf(Sr[c] - mx);     Sr[c] = e0;     s0 += e0;
      float e1 = __expf(Sr[c + 1] - mx); Sr[c + 1] = e1; s1 += e1;
      float e2 = __expf(Sr[c + 2] - mx); Sr[c + 2] = e2; s2 += e2;
      float e3 = __expf(Sr[c + 3] - mx); Sr[c + 3] = e3; s3 += e3;
    }
    float sum = (s0 + s1) + (s2 + s3);
    sum += __shfl_xor(sum, 1);
    sum += __shfl_xor(sum, 2);
    sum += __shfl_xor(sum, 4);
    float inv = 1.0f / sum;
    int qrow = qBase + r;
    if (qrow < 300) {
#pragma unroll
      for (int i = 0; i < 5; ++i) {
        int cb = c0 + i * 8;
        union { unsigned short u[8]; s16x8 v; } o;
#pragma unroll
        for (int e = 0; e < 8; ++e) {
          int cc = cb + e;
          o.u[e] = (cc < 300) ? f2bf(Sr[cc] * inv) : (unsigned short)0;
        }
        *(s16x8*)(Pb + (size_t)qrow * SP + cb) = o.v;
      }
    }
  }
}

// ---- K3: O = P @ V  (A = P [300][320], B^T = Vt [512][320], C fp32) -------
__global__ __launch_bounds__(256) void k_pv(const unsigned short* __restrict__ P,
                                            const unsigned short* __restrict__ Vt,
                                            float* __restrict__ O) {
  __shared__ short As[128 * 32];
  __shared__ short Bs[128 * 32];
  int bid = blockIdx.x;                       // 3072 = 8*384, 384 = 32*12
  int xc = bid & 7, j = bid >> 3;
  int b = xc + 8 * (j / 12);
  int tile = j % 12;
  int mt = tile >> 2, n0 = (tile & 3) * 128;
  int rowBase = mt * 128;
  const unsigned short* Pb  = P  + (size_t)b * S_ * SP;
  const unsigned short* Vtb = Vt + (size_t)b * 512 * SP;
  float* Ob = O + (size_t)b * S_ * 512;
  int tid = threadIdx.x, lane = tid & 63, wid = tid >> 6;
  int wr = wid >> 1, wc = wid & 1;
  int sr4 = lane >> 2;
  int ss = ((lane & 3) ^ ((lane >> 3) & 3)) * 8;
  int fr = lane & 15;
  int g = lane >> 4;
  int sl = (g ^ ((fr >> 1) & 3)) * 8;
  f32x4 acc[4][4] = {};

  for (int t = 0; t < 10; ++t) {
    int k0 = t * 32;
    for (int c = wid * 2; c < wid * 2 + 2; ++c) {
      int row = rowBase + c * 16 + sr4; if (row > 299) row = 299;
      glds16(Pb + (size_t)row * SP + k0 + ss, &As[c * 512 + lane * 8]);
    }
    for (int c = wid * 2; c < wid * 2 + 2; ++c)
      glds16(Vtb + (size_t)(n0 + c * 16 + sr4) * SP + k0 + ss,
             &Bs[c * 512 + lane * 8]);
    __syncthreads();
    SB8 aF[4], bF[4];
#pragma unroll
    for (int m = 0; m < 4; ++m) {
      int row = wr * 64 + m * 16 + fr;
      aF[m].s = *(const s16x8*)&As[row * 32 + sl];
    }
#pragma unroll
    for (int n = 0; n < 4; ++n) {
      int row = wc * 64 + n * 16 + fr;
      bF[n].s = *(const s16x8*)&Bs[row * 32 + sl];
    }
#pragma unroll
    for (int m = 0; m < 4; ++m)
#pragma unroll
      for (int n = 0; n < 4; ++n)
        acc[m][n] = __builtin_amdgcn_mfma_f32_16x16x32_bf16(aF[m].b, bF[n].b, acc[m][n], 0, 0, 0);
    __syncthreads();
  }
  int fq = lane >> 4;
#pragma unroll
  for (int m = 0; m < 4; ++m)
#pragma unroll
    for (int n = 0; n < 4; ++n) {
      int col = n0 + wc * 64 + n * 16 + fr;
#pragma unroll
      for (int jj = 0; jj < 4; ++jj) {
        int row = rowBase + wr * 64 + m * 16 + fq * 4 + jj;
        if (row < 300) Ob[(size_t)row * 512 + col] = acc[m][n][jj];
      }
    }
}

// ---- launcher --------------------------------------------------------------
// G-trick pipeline with PADDED xb/T (stride 544 shorts = 1088 B).
// T padded = 76800*544*2 = 83,558,400 B <= d_out (157 MB).
// ws: Vt@0 (83,886,080), xb@83,886,080 (83,558,400), P@167,444,480
// (49,152,000), wtv@216,596,480 (524,288), wb01@217,120,768 (1,048,576),
// Gjd@218,169,344 (524,288) = 218.7 MB total.
extern "C" void kernel_launch(void* const* d_in, const int* in_sizes, int n_in,
                              void* d_out, int out_size, void* d_ws, size_t ws_size,
                              hipStream_t stream) {
  const float* x = (const float*)d_in[0];
  const float* w = (const float*)d_in[1];
  float* out = (float*)d_out;
  char* ws = (char*)d_ws;

  unsigned short* Tq   = (unsigned short*)d_out;              // T in d_out
  unsigned short* Vt   = (unsigned short*)(ws);
  unsigned short* xb   = (unsigned short*)(ws + 83886080LL);
  unsigned short* Pp   = (unsigned short*)(ws + 167444480LL);
  unsigned short* wtv  = (unsigned short*)(ws + 216596480LL);
  unsigned short* wb01 = (unsigned short*)(ws + 217120768LL);
  unsigned short* Gjd  = (unsigned short*)(ws + 218169344LL);

  k_cvt_x<<<2048, 256, 0, stream>>>(x, xb, 4915200);
  k_wt2<<<3072, 256, 0, stream>>>(w, wb01, wtv);
  k_G<<<16, 256, 0, stream>>>(wb01, Gjd);
  k_projT<<<2400, 256, 0, stream>>>(xb, Gjd, Tq);             // T -> d_out
  k_attn_p<<<2560, 256, 0, stream>>>(Tq, xb, Pp);             // K == xb
  k_projV<<<2400, 256, 0, stream>>>(xb, wtv, Vt);
  k_pv<<<3072, 256, 0, stream>>>(Pp, Vt, out);                // overwrites T
}

// Round 23
// 346.152 us; speedup vs baseline: 1.0896x; 1.0546x over previous
//
#include <hip/hip_runtime.h>
#include <hip/hip_bf16.h>
#include <math.h>

// ---- types ----------------------------------------------------------------
typedef __attribute__((ext_vector_type(8))) __bf16 bf16x8;
typedef __attribute__((ext_vector_type(8))) short  s16x8;
typedef __attribute__((ext_vector_type(4))) float  f32x4;
union SB8 { s16x8 s; bf16x8 b; };

__device__ __forceinline__ unsigned short f2bf(float f) {
  unsigned int u = __builtin_bit_cast(unsigned int, f);
  u = u + 0x7FFFu + ((u >> 16) & 1u);           // round-to-nearest-even
  return (unsigned short)(u >> 16);
}

// async global->LDS, 16B per lane; LDS dest = wave-uniform base + lane*16
__device__ __forceinline__ void glds16(const void* g, void* l) {
  __builtin_amdgcn_global_load_lds((const __attribute__((address_space(1))) void*)g,
                                   (__attribute__((address_space(3))) void*)l, 16, 0, 0);
}

#define B_  256
#define S_  300
#define D_  512
#define SP  320          // keys padded to 320 (zero pad)
#define M_  76800        // B_*S_
#define XS  544          // padded row stride (shorts) for xb and T: 1088 B
                         // (1024B stride aliased 16 rows into 4 L2 channels)

// ---- K0: x fp32 -> bf16, PADDED rows (512 data + 32 pad shorts) -----------
__global__ __launch_bounds__(256) void k_cvt_x(const float* __restrict__ x,
                                               unsigned short* __restrict__ xb, int n8) {
  int i = blockIdx.x * blockDim.x + threadIdx.x;
  int stride = gridDim.x * blockDim.x;
  for (; i < n8; i += stride) {
    const float4* p = (const float4*)(x + (size_t)i * 8);
    float4 a = p[0], b = p[1];
    union { unsigned short u[8]; s16x8 v; } o;
    o.u[0]=f2bf(a.x); o.u[1]=f2bf(a.y); o.u[2]=f2bf(a.z); o.u[3]=f2bf(a.w);
    o.u[4]=f2bf(b.x); o.u[5]=f2bf(b.y); o.u[6]=f2bf(b.z); o.u[7]=f2bf(b.w);
    int row = i >> 6, c8 = i & 63;               // 64 chunks of 8 per row
    *(s16x8*)(xb + (size_t)row * XS + c8 * 8) = o.v;
  }
}

// ---- K0b: w -> wb01 (Wq,Wk row-major bf16) + wtv (Wv transposed bf16) -----
__global__ __launch_bounds__(256) void k_wt2(const float* __restrict__ w,
                                             unsigned short* __restrict__ wb01,
                                             unsigned short* __restrict__ wtv) {
  int i = blockIdx.x * 256 + threadIdx.x;       // exactly 3*512*512 threads
  int p = i >> 18;
  int r = i & 262143;
  unsigned short v = f2bf(w[i]);
  if (p < 2) {
    wb01[p * 262144 + r] = v;                   // row-major (coalesced)
  } else {
    int k = r >> 9, n = r & 511;
    wtv[n * 512 + k] = v;                       // n-major for k_projV
  }
}

// ---- K0c: Gjd[j][d] = sum_e Wk[j][e] * Wq[d][e]  (512x512, 16 blocks) -----
__global__ __launch_bounds__(256) void k_G(const unsigned short* __restrict__ wb01,
                                           unsigned short* __restrict__ gjd) {
  __shared__ short As[2][128 * 64];
  __shared__ short Bs[2][128 * 64];
  const unsigned short* wa = wb01 + 262144;     // Wk
  const unsigned short* wb = wb01;              // Wq
  int bid = blockIdx.x;                         // 16 = 4 x 4
  int mt = bid >> 2, n0 = (bid & 3) * 128;
  int rowBase = mt * 128;

  int tid = threadIdx.x, lane = tid & 63, wid = tid >> 6;
  int wr = wid >> 1, wc = wid & 1;
  int sr = lane >> 3;
  int ssg = ((lane & 7) ^ sr) * 8;
  int fr = lane & 15;
  int g  = lane >> 4;
  f32x4 acc[4][4] = {};

  for (int c = wid * 4; c < wid * 4 + 4; ++c) {
    glds16(wa + (size_t)(rowBase + c * 8 + sr) * 512 + ssg, &As[0][c * 512 + lane * 8]);
    glds16(wb + (size_t)(n0 + c * 8 + sr) * 512 + ssg, &Bs[0][c * 512 + lane * 8]);
  }
  __syncthreads();

  for (int t = 0; t < 8; ++t) {
    int cur = t & 1;
    if (t < 7) {
      int k0n = (t + 1) * 64;
      for (int c = wid * 4; c < wid * 4 + 4; ++c) {
        glds16(wa + (size_t)(rowBase + c * 8 + sr) * 512 + k0n + ssg,
               &As[cur ^ 1][c * 512 + lane * 8]);
        glds16(wb + (size_t)(n0 + c * 8 + sr) * 512 + k0n + ssg,
               &Bs[cur ^ 1][c * 512 + lane * 8]);
      }
    }
    SB8 aF[4][2], bF[4][2];
#pragma unroll
    for (int m = 0; m < 4; ++m) {
      int row = wr * 64 + m * 16 + fr;
#pragma unroll
      for (int kk = 0; kk < 2; ++kk) {
        int sl = ((kk << 2) + g) ^ (fr & 7);
        aF[m][kk].s = *(const s16x8*)&As[cur][row * 64 + sl * 8];
      }
    }
#pragma unroll
    for (int n = 0; n < 4; ++n) {
      int row = wc * 64 + n * 16 + fr;
#pragma unroll
      for (int kk = 0; kk < 2; ++kk) {
        int sl = ((kk << 2) + g) ^ (fr & 7);
        bF[n][kk].s = *(const s16x8*)&Bs[cur][row * 64 + sl * 8];
      }
    }
#pragma unroll
    for (int kk = 0; kk < 2; ++kk)
#pragma unroll
      for (int m = 0; m < 4; ++m)
#pragma unroll
        for (int n = 0; n < 4; ++n)
          acc[m][n] = __builtin_amdgcn_mfma_f32_16x16x32_bf16(aF[m][kk].b, bF[n][kk].b,
                                                              acc[m][n], 0, 0, 0);
    __syncthreads();
  }

  int fq = lane >> 4;
#pragma unroll
  for (int m = 0; m < 4; ++m)
#pragma unroll
    for (int n = 0; n < 4; ++n) {
      int row = rowBase + wr * 64 + m * 16 + fq * 4;
      int col = n0 + wc * 64 + n * 16 + fr;
      unsigned short* o = gjd + (size_t)row * 512 + col;
#pragma unroll
      for (int jj = 0; jj < 4; ++jj)
        o[(size_t)jj * 512] = f2bf(acc[m][n][jj]);
    }
}

// ---- K1a: T = xb . G  (single score-side projection; G = Wq Wk^T) ---------
__global__ __launch_bounds__(256) void k_projT(const unsigned short* __restrict__ xb,
                                               const unsigned short* __restrict__ gjd,
                                               unsigned short* __restrict__ Tout) {
  __shared__ short As[2][128 * 64];
  __shared__ short Bs[2][128 * 64];
  int bid = blockIdx.x;               // 2400 = 8 x 300; 300 = 75 x 4
  int xc = bid & 7, j = bid >> 3;
  int mt = xc + 8 * (j >> 2);
  int n0 = (j & 3) * 128;
  int rowBase = mt * 128;

  int tid = threadIdx.x, lane = tid & 63, wid = tid >> 6;
  int wr = wid >> 1, wc = wid & 1;
  int sr = lane >> 3;
  int ssg = ((lane & 7) ^ sr) * 8;
  int fr = lane & 15;
  int g  = lane >> 4;
  f32x4 acc[4][4] = {};

  for (int c = wid * 4; c < wid * 4 + 4; ++c) {
    glds16(xb + (size_t)(rowBase + c * 8 + sr) * XS + ssg, &As[0][c * 512 + lane * 8]);
    glds16(gjd + (size_t)(n0 + c * 8 + sr) * 512 + ssg, &Bs[0][c * 512 + lane * 8]);
  }
  __syncthreads();

  for (int t = 0; t < 8; ++t) {
    int cur = t & 1;
    if (t < 7) {
      int k0n = (t + 1) * 64;
      for (int c = wid * 4; c < wid * 4 + 4; ++c) {
        glds16(xb + (size_t)(rowBase + c * 8 + sr) * XS + k0n + ssg,
               &As[cur ^ 1][c * 512 + lane * 8]);
        glds16(gjd + (size_t)(n0 + c * 8 + sr) * 512 + k0n + ssg,
               &Bs[cur ^ 1][c * 512 + lane * 8]);
      }
    }
    SB8 aF[4][2], bF[4][2];
#pragma unroll
    for (int m = 0; m < 4; ++m) {
      int row = wr * 64 + m * 16 + fr;
#pragma unroll
      for (int kk = 0; kk < 2; ++kk) {
        int sl = ((kk << 2) + g) ^ (fr & 7);
        aF[m][kk].s = *(const s16x8*)&As[cur][row * 64 + sl * 8];
      }
    }
#pragma unroll
    for (int n = 0; n < 4; ++n) {
      int row = wc * 64 + n * 16 + fr;
#pragma unroll
      for (int kk = 0; kk < 2; ++kk) {
        int sl = ((kk << 2) + g) ^ (fr & 7);
        bF[n][kk].s = *(const s16x8*)&Bs[cur][row * 64 + sl * 8];
      }
    }
#pragma unroll
    for (int kk = 0; kk < 2; ++kk)
#pragma unroll
      for (int m = 0; m < 4; ++m)
#pragma unroll
        for (int n = 0; n < 4; ++n)
          acc[m][n] = __builtin_amdgcn_mfma_f32_16x16x32_bf16(aF[m][kk].b, bF[n][kk].b,
                                                              acc[m][n], 0, 0, 0);
    __syncthreads();
  }

  int fq = lane >> 4;
#pragma unroll
  for (int m = 0; m < 4; ++m)
#pragma unroll
    for (int n = 0; n < 4; ++n) {
      int row = rowBase + wr * 64 + m * 16 + fq * 4;
      int col = n0 + wc * 64 + n * 16 + fr;
      unsigned short* o = Tout + (size_t)row * XS + col;
#pragma unroll
      for (int jj = 0; jj < 4; ++jj)
        o[(size_t)jj * XS] = f2bf(acc[m][n][jj]);
    }
}

// ---- K1b: V projection -> Vt[b][512][320]; xb read at padded stride -------
__global__ __launch_bounds__(256) void k_projV(const unsigned short* __restrict__ xb,
                                               const unsigned short* __restrict__ wtv,
                                               unsigned short* __restrict__ vt) {
  __shared__ short As[2][128 * 64];   // 2 x 16 KB (reused as T2, 32 KB)
  __shared__ short Bs[2][128 * 64];   // 2 x 16 KB
  int bid = blockIdx.x;               // 2400 = 8 x 300; 300 = 75 x 4
  int xc = bid & 7, j = bid >> 3;
  int mt = xc + 8 * (j >> 2);
  int n0 = (j & 3) * 128;
  int rowBase = mt * 128;
  const unsigned short* wp = wtv;

  int tid = threadIdx.x, lane = tid & 63, wid = tid >> 6;
  int wr = wid >> 1, wc = wid & 1;
  int sr = lane >> 3;
  int ssg = ((lane & 7) ^ sr) * 8;
  int fr = lane & 15;
  int g  = lane >> 4;
  f32x4 acc[4][4] = {};

  for (int c = wid * 4; c < wid * 4 + 4; ++c) {
    glds16(xb + (size_t)(rowBase + c * 8 + sr) * XS + ssg, &As[0][c * 512 + lane * 8]);
    glds16(wp + (size_t)(n0 + c * 8 + sr) * 512 + ssg, &Bs[0][c * 512 + lane * 8]);
  }
  __syncthreads();

  for (int t = 0; t < 8; ++t) {
    int cur = t & 1;
    if (t < 7) {
      int k0n = (t + 1) * 64;
      for (int c = wid * 4; c < wid * 4 + 4; ++c) {
        glds16(xb + (size_t)(rowBase + c * 8 + sr) * XS + k0n + ssg,
               &As[cur ^ 1][c * 512 + lane * 8]);
        glds16(wp + (size_t)(n0 + c * 8 + sr) * 512 + k0n + ssg,
               &Bs[cur ^ 1][c * 512 + lane * 8]);
      }
    }
    SB8 aF[4][2], bF[4][2];
#pragma unroll
    for (int m = 0; m < 4; ++m) {
      int row = wr * 64 + m * 16 + fr;
#pragma unroll
      for (int kk = 0; kk < 2; ++kk) {
        int sl = ((kk << 2) + g) ^ (fr & 7);
        aF[m][kk].s = *(const s16x8*)&As[cur][row * 64 + sl * 8];
      }
    }
#pragma unroll
    for (int n = 0; n < 4; ++n) {
      int row = wc * 64 + n * 16 + fr;
#pragma unroll
      for (int kk = 0; kk < 2; ++kk) {
        int sl = ((kk << 2) + g) ^ (fr & 7);
        bF[n][kk].s = *(const s16x8*)&Bs[cur][row * 64 + sl * 8];
      }
    }
#pragma unroll
    for (int kk = 0; kk < 2; ++kk)
#pragma unroll
      for (int m = 0; m < 4; ++m)
#pragma unroll
        for (int n = 0; n < 4; ++n)
          acc[m][n] = __builtin_amdgcn_mfma_f32_16x16x32_bf16(aF[m][kk].b, bF[n][kk].b,
                                                              acc[m][n], 0, 0, 0);
    __syncthreads();
  }

  // epilogue v2 (round-15 proven): n-major swizzled T2, coalesced 8B stores
  int fq = lane >> 4;
  short* T2 = &As[0][0];                   // 16384 shorts = [128 n][128 s']
#pragma unroll
  for (int m = 0; m < 4; ++m) {
    int s0 = wr * 64 + m * 16 + fq * 4;
#pragma unroll
    for (int n16 = 0; n16 < 4; ++n16) {
      int c = wc * 64 + n16 * 16 + fr;
      int idx = c * 128 + (s0 ^ ((c & 7) << 4));
      union { unsigned short u[4]; uint2 v; } w;
#pragma unroll
      for (int jj = 0; jj < 4; ++jj) w.u[jj] = f2bf(acc[m][n16][jj]);
      *(uint2*)&T2[idx] = w.v;
    }
  }
  __syncthreads();
  for (int i = 0; i < 8; ++i) {
    int u = i * 256 + tid;
    int n = u >> 4, ch = u & 15;
    int idx = n * 128 + ((ch * 8) ^ ((n & 7) << 4));
    s16x8 vv = *(const s16x8*)&T2[idx];
    size_t ncol = (size_t)(n0 + n);
#pragma unroll
    for (int h = 0; h < 2; ++h) {
      int gs = rowBase + ch * 8 + h * 4;
      int bb = (unsigned)gs / 300u;
      int sloc = gs - bb * 300;
      union { unsigned short u[4]; uint2 v; } w;
#pragma unroll
      for (int e = 0; e < 4; ++e) w.u[e] = (unsigned short)vv[h * 4 + e];
      *(uint2*)(vt + (size_t)bb * (512 * SP) + ncol * SP + sloc) = w.v;
    }
  }
}

// ---- K2: P = softmax(T x^T / sqrt(300)) per (batch, 64-row q-tile) --------
// v11: 64-row q-tiles (grid 1280). 9 loads feed 20 MFMAs per iter (was
// 7/10) -- K fragments reused across 2x q-rows, ~36% fewer line-requests
// per FLOP (the TA request rate is the residual limiter after padding).
// Softmax runs in two 32-row phases reusing the same 41KB S buffer.
__global__ __launch_bounds__(256) void k_attn_p(const unsigned short* __restrict__ Q,
                                                const unsigned short* __restrict__ K,
                                                unsigned short* __restrict__ P) {
  __shared__ float S[32 * 321];              // 41,088 B
  int bid = blockIdx.x;                      // 1280 = 8 x 160
  int xcd = bid & 7, slot = bid >> 3;
  int b = xcd * 32 + slot / 5;
  int qt = slot % 5;
  int qBase = qt * 64;
  const unsigned short* Qb = Q + (size_t)b * S_ * XS;
  const unsigned short* Kb = K + (size_t)b * S_ * XS;
  unsigned short* Pb = P + (size_t)b * S_ * SP;
  int tid = threadIdx.x, lane = tid & 63, wid = tid >> 6;
  int kg = (lane >> 4) * 8, fr = lane & 15;
  int g = lane >> 4;

  // per-lane Q fragment rows for the 4 q-sub-tiles (clamped; masked at write)
  const unsigned short* Qr[4];
#pragma unroll
  for (int m = 0; m < 4; ++m) {
    int qr = qBase + m * 16 + fr; if (qr > 299) qr = 299;
    Qr[m] = Qb + (size_t)qr * XS + kg;
  }
  // per-lane K fragment rows for this wave's 5 key-tiles (clamped)
  int ntBase = wid * 5;
  const unsigned short* Kr[5];
#pragma unroll
  for (int n = 0; n < 5; ++n) {
    int kr = (ntBase + n) * 16 + fr; if (kr > 299) kr = 299;
    Kr[n] = Kb + (size_t)kr * XS + kg;
  }

  f32x4 acc[4][5] = {};
#pragma unroll
  for (int t = 0; t < 16; ++t) {
    int k0 = t * 32;
    SB8 qF[4], kF[5];
#pragma unroll
    for (int m = 0; m < 4; ++m) qF[m].s = *(const s16x8*)(Qr[m] + k0);
#pragma unroll
    for (int n = 0; n < 5; ++n) kF[n].s = *(const s16x8*)(Kr[n] + k0);
#pragma unroll
    for (int m = 0; m < 4; ++m)
#pragma unroll
      for (int n = 0; n < 5; ++n)
        acc[m][n] = __builtin_amdgcn_mfma_f32_16x16x32_bf16(qF[m].b, kF[n].b, acc[m][n], 0, 0, 0);
  }

  const float scale = 0.05773502691896258f;      // 1/sqrt(300)
#pragma unroll
  for (int ph = 0; ph < 2; ++ph) {
    // spill rows ph*32 .. ph*32+31 (acc[2ph], acc[2ph+1])
#pragma unroll
    for (int mh = 0; mh < 2; ++mh) {
      int m = ph * 2 + mh;
#pragma unroll
      for (int n = 0; n < 5; ++n) {
        int col = (ntBase + n) * 16 + fr;
        int rb = mh * 16 + g * 4;
#pragma unroll
        for (int jj = 0; jj < 4; ++jj)
          S[(rb + jj) * 321 + col] = acc[m][n][jj] * scale;
      }
    }
    __syncthreads();
    // fused softmax + P write: 8 threads per row, thread-local S cells.
    {
      int r = tid >> 3, jj = tid & 7;
      int c0 = jj * 40;
      int cend = c0 + 40; if (cend > 300) cend = 300;
      float* Sr = &S[r * 321];
      float m0 = -1e30f, m1 = -1e30f, m2 = -1e30f, m3 = -1e30f;
      for (int c = c0; c < cend; c += 4) {
        m0 = fmaxf(m0, Sr[c]);     m1 = fmaxf(m1, Sr[c + 1]);
        m2 = fmaxf(m2, Sr[c + 2]); m3 = fmaxf(m3, Sr[c + 3]);
      }
      float mx = fmaxf(fmaxf(m0, m1), fmaxf(m2, m3));
      mx = fmaxf(mx, __shfl_xor(mx, 1));
      mx = fmaxf(mx, __shfl_xor(mx, 2));
      mx = fmaxf(mx, __shfl_xor(mx, 4));
      float s0 = 0.f, s1 = 0.f, s2 = 0.f, s3 = 0.f;
      for (int c = c0; c < cend; c += 4) {
        float e0 = __expf(Sr[c] - mx);     Sr[c] = e0;     s0 += e0;
        float e1 = __expf(Sr[c + 1] - mx); Sr[c + 1] = e1; s1 += e1;
        float e2 = __expf(Sr[c + 2] - mx); Sr[c + 2] = e2; s2 += e2;
        float e3 = __expf(Sr[c + 3] - mx); Sr[c + 3] = e3; s3 += e3;
      }
      float sum = (s0 + s1) + (s2 + s3);
      sum += __shfl_xor(sum, 1);
      sum += __shfl_xor(sum, 2);
      sum += __shfl_xor(sum, 4);
      float inv = 1.0f / sum;
      int qrow = qBase + ph * 32 + r;
      if (qrow < 300) {
#pragma unroll
        for (int i = 0; i < 5; ++i) {
          int cb = c0 + i * 8;
          union { unsigned short u[8]; s16x8 v; } o;
#pragma unroll
          for (int e = 0; e < 8; ++e) {
            int cc = cb + e;
            o.u[e] = (cc < 300) ? f2bf(Sr[cc] * inv) : (unsigned short)0;
          }
          *(s16x8*)(Pb + (size_t)qrow * SP + cb) = o.v;
        }
      }
    }
    if (ph == 0) __syncthreads();              // S reads done before respill
  }
}

// ---- K3: O = P @ V  (A = P [300][320], B^T = Vt [512][320], C fp32) -------
__global__ __launch_bounds__(256) void k_pv(const unsigned short* __restrict__ P,
                                            const unsigned short* __restrict__ Vt,
                                            float* __restrict__ O) {
  __shared__ short As[128 * 32];
  __shared__ short Bs[128 * 32];
  int bid = blockIdx.x;                       // 3072 = 8*384, 384 = 32*12
  int xc = bid & 7, j = bid >> 3;
  int b = xc + 8 * (j / 12);
  int tile = j % 12;
  int mt = tile >> 2, n0 = (tile & 3) * 128;
  int rowBase = mt * 128;
  const unsigned short* Pb  = P  + (size_t)b * S_ * SP;
  const unsigned short* Vtb = Vt + (size_t)b * 512 * SP;
  float* Ob = O + (size_t)b * S_ * 512;
  int tid = threadIdx.x, lane = tid & 63, wid = tid >> 6;
  int wr = wid >> 1, wc = wid & 1;
  int sr4 = lane >> 2;
  int ss = ((lane & 3) ^ ((lane >> 3) & 3)) * 8;
  int fr = lane & 15;
  int g = lane >> 4;
  int sl = (g ^ ((fr >> 1) & 3)) * 8;
  f32x4 acc[4][4] = {};

  for (int t = 0; t < 10; ++t) {
    int k0 = t * 32;
    for (int c = wid * 2; c < wid * 2 + 2; ++c) {
      int row = rowBase + c * 16 + sr4; if (row > 299) row = 299;
      glds16(Pb + (size_t)row * SP + k0 + ss, &As[c * 512 + lane * 8]);
    }
    for (int c = wid * 2; c < wid * 2 + 2; ++c)
      glds16(Vtb + (size_t)(n0 + c * 16 + sr4) * SP + k0 + ss,
             &Bs[c * 512 + lane * 8]);
    __syncthreads();
    SB8 aF[4], bF[4];
#pragma unroll
    for (int m = 0; m < 4; ++m) {
      int row = wr * 64 + m * 16 + fr;
      aF[m].s = *(const s16x8*)&As[row * 32 + sl];
    }
#pragma unroll
    for (int n = 0; n < 4; ++n) {
      int row = wc * 64 + n * 16 + fr;
      bF[n].s = *(const s16x8*)&Bs[row * 32 + sl];
    }
#pragma unroll
    for (int m = 0; m < 4; ++m)
#pragma unroll
      for (int n = 0; n < 4; ++n)
        acc[m][n] = __builtin_amdgcn_mfma_f32_16x16x32_bf16(aF[m].b, bF[n].b, acc[m][n], 0, 0, 0);
    __syncthreads();
  }
  int fq = lane >> 4;
#pragma unroll
  for (int m = 0; m < 4; ++m)
#pragma unroll
    for (int n = 0; n < 4; ++n) {
      int col = n0 + wc * 64 + n * 16 + fr;
#pragma unroll
      for (int jj = 0; jj < 4; ++jj) {
        int row = rowBase + wr * 64 + m * 16 + fq * 4 + jj;
        if (row < 300) Ob[(size_t)row * 512 + col] = acc[m][n][jj];
      }
    }
}

// ---- launcher --------------------------------------------------------------
// G-trick pipeline with PADDED xb/T (stride 544 shorts = 1088 B).
// ws: Vt@0 (83,886,080), xb@83,886,080 (83,558,400), P@167,444,480
// (49,152,000), wtv@216,596,480 (524,288), wb01@217,120,768 (1,048,576),
// Gjd@218,169,344 (524,288) = 218.7 MB total.
extern "C" void kernel_launch(void* const* d_in, const int* in_sizes, int n_in,
                              void* d_out, int out_size, void* d_ws, size_t ws_size,
                              hipStream_t stream) {
  const float* x = (const float*)d_in[0];
  const float* w = (const float*)d_in[1];
  float* out = (float*)d_out;
  char* ws = (char*)d_ws;

  unsigned short* Tq   = (unsigned short*)d_out;              // T in d_out
  unsigned short* Vt   = (unsigned short*)(ws);
  unsigned short* xb   = (unsigned short*)(ws + 83886080LL);
  unsigned short* Pp   = (unsigned short*)(ws + 167444480LL);
  unsigned short* wtv  = (unsigned short*)(ws + 216596480LL);
  unsigned short* wb01 = (unsigned short*)(ws + 217120768LL);
  unsigned short* Gjd  = (unsigned short*)(ws + 218169344LL);

  k_cvt_x<<<2048, 256, 0, stream>>>(x, xb, 4915200);
  k_wt2<<<3072, 256, 0, stream>>>(w, wb01, wtv);
  k_G<<<16, 256, 0, stream>>>(wb01, Gjd);
  k_projT<<<2400, 256, 0, stream>>>(xb, Gjd, Tq);             // T -> d_out
  k_attn_p<<<1280, 256, 0, stream>>>(Tq, xb, Pp);             // K == xb
  k_projV<<<2400, 256, 0, stream>>>(xb, wtv, Vt);
  k_pv<<<3072, 256, 0, stream>>>(Pp, Vt, out);                // overwrites T
}